// Round 7
// baseline (1590.722 us; speedup 1.0000x reference)
//
#include <hip/hip_runtime.h>
#include <math.h>

// ============================================================
// PointerDecoderSort — MFMA bf16, 32x32 tiles for fat GEMMs.
// R7: v_mfma_f32_32x32x16_bf16 for phase1b/qkv/attn_out/ffn1/ffn2/kproj
// (16 FLOP/B of fragment traffic vs 8 for 16x16 — halves the measured
// dominant LDS-read pipe). Scores/PV/S stay 16x16x32. Head pairs are
// processed per phase (2 SB buffers) cutting attention barriers 44->16;
// softmax writes pF directly (one b128/thread, P-split pass removed).
//
// Layout facts:
//   16x16x32: A[m=lane&15][k=(lane>>4)*8+j]; B[k=(lane>>4)*8+j][n=lane&15]
//             C/D: col=lane&15, row=(lane>>4)*4+reg            (m89/m91)
//   32x32x16: A[m=lane&31][k=(lane>>5)*8+j]; B[k=(lane>>5)*8+j][n=lane&31]
//             C/D: col=lane&31, row=(reg&3)+8*(reg>>2)+4*(lane>>5) (m74/m101)
// ============================================================

typedef __attribute__((ext_vector_type(8)))  short bf16x8;
typedef __attribute__((ext_vector_type(4)))  float f32x4;
typedef __attribute__((ext_vector_type(16))) float f32x16;

#define NEG_FILL (-3.0e38f)   // finite stand-in for -inf (inf-inf = nan in harness diff)

// ---- ws layout (units of 8 shorts = 16 B) ----
#define U_Q    0        // 2048  : Q rank queries, A-FO-16 [4mt][8kb32][64]
#define U_VE   2048     // 4096  : ve_w2  B-FO-32 [8nt][8kb16][64]
#define U_QKV  6144     // 24576 : attn_in_w B-FO-32 [24nt][16kb][64]
#define U_WO   30720    // 8192  : attn_out_w B-FO-32 [8nt][16kb][64]
#define U_F1   38912    // 32768 : ffn_w1 B-FO-32 [32nt][16kb][64]
#define U_F2   71680    // 32768 : ffn_w2 B-FO-32 [8nt][64kb][64]
#define U_KW   104448   // 8192  : k_w B-FO-32 [8nt][16kb][64]
#define U_TOT  112640   // *16B = 1,802,240 B in d_ws

// ---- LDS layout (shorts) ----
#define SH_H  0         // h residual, A-FO-32 [2mi][16kb][64][8] = 16384
#define SH_A  16384     // phase-shared region, 24576 shorts:
//   ve phase : rbuf A-FO-32 [2mi][8kb][64][8] = 8192
//   ffn phase: f1   A-FO-32 [2mi][16kb][64][8] = 16384
//   attention: qF(e) SH_A + e*2048          A-FO-16 [4mi16][64][8]
//              kF(e) SH_A + 4096  + e*2048  B-FO-16 [4nt16][64][8]
//              vF(e) SH_A + 8192  + e*2048  B-FO-16 [2nt16][2kb][64][8]
//              pF(e) SH_A + 12288 + e*4096  A-FO-16 [4mt][2kb][64][8]
//              aoF   SH_A + 20480           A-FO-32 [2mi2][4ks][64][8]
#define SH_SHORTS 40960
// floats after shorts:
#define FB_SB   0       // 2 score buffers [2][64][65]
#define FB_XR   8320    // 64 x values
#define FB_FLOATS 8384
#define LDS_BYTES (SH_SHORTS*2 + FB_FLOATS*4)   // 115456

__device__ __forceinline__ unsigned short f2bf(float f){
  unsigned u = __float_as_uint(f);
  return (unsigned short)((u + 0x7FFFu + ((u>>16)&1u)) >> 16);
}
__device__ __forceinline__ float bf2f(unsigned short h){
  return __uint_as_float(((unsigned)h) << 16);
}

#define MFMA16(a,b,c) __builtin_amdgcn_mfma_f32_16x16x32_bf16((a),(b),(c),0,0,0)
#define MFMA32(a,b,c) __builtin_amdgcn_mfma_f32_32x32x16_bf16((a),(b),(c),0,0,0)

// ------------------------------------------------------------
__global__ void __launch_bounds__(256) prep_q(const float* __restrict__ rank_emb,
                                              const float* __restrict__ q_w,
                                              const float* __restrict__ q_b,
                                              short* __restrict__ wsp) {
    int t = blockIdx.x;
    int c = threadIdx.x;
    float acc = q_b[c];
    for (int d = 0; d < 256; d += 4) {
        acc += rank_emb[t*256 + d + 0] * q_w[(d+0)*256 + c]
             + rank_emb[t*256 + d + 1] * q_w[(d+1)*256 + c]
             + rank_emb[t*256 + d + 2] * q_w[(d+2)*256 + c]
             + rank_emb[t*256 + d + 3] * q_w[(d+3)*256 + c];
    }
    // A-FO-16: [mt=t>>4][kb=c>>5][lane=(c>>3&3)*16 + (t&15)][j=c&7]
    int kb = c >> 5, lane = ((c>>3)&3)*16 + (t&15), j = c & 7;
    int u = ((t>>4)*8 + kb)*64 + lane;
    wsp[(U_Q + u)*8 + j] = (short)f2bf(acc);
}

// ------------------------------------------------------------
// prep_w: B-FO-32 for all weights: unit[nt][kb16][lane], lane holds
// B[k = kb*16 + (lane>>5)*8 + j][n = nt*32 + (lane&31)].
// ------------------------------------------------------------
__global__ void __launch_bounds__(256) prep_w(const float* __restrict__ ve_w2,
                                              const float* __restrict__ attn_in_w,
                                              const float* __restrict__ attn_out_w,
                                              const float* __restrict__ ffn_w1,
                                              const float* __restrict__ ffn_w2,
                                              const float* __restrict__ k_w,
                                              short* __restrict__ wsp) {
    int r = blockIdx.x*256 + threadIdx.x;
    const float* w; int N, K, base;
    if (r < 4096)                { w = ve_w2;      N = 256;  K = 128;  base = U_VE;  }
    else if ((r -= 4096)  < 24576) { w = attn_in_w;  N = 768;  K = 256;  base = U_QKV; }
    else if ((r -= 24576) < 8192)  { w = attn_out_w; N = 256;  K = 256;  base = U_WO;  }
    else if ((r -= 8192)  < 32768) { w = ffn_w1;     N = 1024; K = 256;  base = U_F1;  }
    else if ((r -= 32768) < 32768) { w = ffn_w2;     N = 256;  K = 1024; base = U_F2;  }
    else     { r -= 32768;           w = k_w;        N = 256;  K = 256;  base = U_KW;  }
    int KB = K >> 4;
    int lane = r & 63;
    int kb   = (r >> 6) % KB;
    int nt   = r / (64 * KB);
    int n  = nt*32 + (lane & 31);
    int k0 = kb*16 + (lane >> 5)*8;
    bf16x8 hv;
#pragma unroll
    for (int j = 0; j < 8; j++) hv[j] = (short)f2bf(w[(size_t)(k0 + j)*N + n]);
    *(bf16x8*)&wsp[(size_t)(base + r) * 8] = hv;
}

// ------------------------------------------------------------
// fused per-batch-element kernel: 1024 threads = 16 waves
// ------------------------------------------------------------
__global__ void __launch_bounds__(1024, 4) fused_kernel(
    const float* __restrict__ x,
    const float* __restrict__ ve_w1, const float* __restrict__ ve_b1,
    const float* __restrict__ ve_b2,
    const float* __restrict__ pos_emb,
    const float* __restrict__ attn_in_b,
    const float* __restrict__ attn_out_b,
    const float* __restrict__ ffn_b1, const float* __restrict__ ffn_b2,
    const float* __restrict__ ln1_g, const float* __restrict__ ln1_b,
    const float* __restrict__ ln2_g, const float* __restrict__ ln2_b,
    const float* __restrict__ k_b,
    const short* __restrict__ wsp,
    float* __restrict__ out)
{
    extern __shared__ short sm[];
    float* smf  = (float*)(sm + SH_SHORTS);
    float* SB0  = smf + FB_SB;           // [64][65]
    float* xrow = smf + FB_XR;

    const int tid  = threadIdx.x;
    const int b    = blockIdx.x;
    const int w    = tid >> 6;     // 0..15
    const int lane = tid & 63;
    const int quad = lane >> 4;    // 16x16 use
    const int lcol = lane & 15;    // 16x16 use
    const int col32 = lane & 31;   // 32x32 use
    const int rbase = 4*(lane>>5); // 32x32 C/D row base

    // fat-GEMM tile ownership: (mi2 = w>>3, nt = w&7)
    const int mi2 = w >> 3;
    const int ntf = w & 7;

    const bf16x8* wsv = (const bf16x8*)wsp;
    const bf16x8* HFu = (const bf16x8*)&sm[SH_H];

    // ---------- phase 0: x row ----------
    if (tid < 64) xrow[tid] = x[b*64 + tid];
    __syncthreads();

    // ---------- phase 1a: rbuf = relu(x*w1+b1), A-FO-32 [2mi][8kb][64][8] ----------
    {
        int u = tid;
        int l3 = u & 63, kb = (u >> 6) & 7, mi = u >> 9;
        int m  = mi*32 + (l3 & 31);
        int k0 = kb*16 + (l3 >> 5)*8;
        float xv = xrow[m];
        bf16x8 hv;
#pragma unroll
        for (int j = 0; j < 8; j++) {
            float f = xv * ve_w1[k0 + j] + ve_b1[k0 + j];
            hv[j] = (short)f2bf(f > 0.f ? f : 0.f);
        }
        *(bf16x8*)&sm[SH_A + u*8] = hv;
    }
    __syncthreads();

    // ---------- phase 1b: h = rbuf @ ve_w2 + b2 + pos  (M64 K128 N256, 32x32) ----------
    {
        f32x16 acc = (f32x16)(0.f);
#pragma unroll
        for (int kb = 0; kb < 8; kb++) {
            bf16x8 ah = *(const bf16x8*)&sm[SH_A + ((mi2*8+kb)*64 + lane)*8];
            bf16x8 bh = wsv[U_VE + (ntf*8+kb)*64 + lane];
            acc = MFMA32(ah, bh, acc);
        }
        __syncthreads();   // rbuf reads complete (SH_A reused by attention)
        int n = ntf*32 + col32;
        float bb = ve_b2[n];
#pragma unroll
        for (int reg = 0; reg < 16; reg++) {
            int r32 = (reg&3) + 8*(reg>>2) + rbase;
            int m = mi2*32 + r32;
            float val = acc[reg] + bb + pos_emb[m*256 + n];
            // h A-FO-32: (m,k=n)
            sm[SH_H + (((mi2*16 + (n>>4))*64) + r32 + 32*((n>>3)&1))*8 + (n&7)] = (short)f2bf(val);
        }
    }
    __syncthreads();

    // ---------- attention: head pairs ----------
    f32x16 aoacc = (f32x16)(0.f);   // attn-out accum: tile (mi2, ntf)

    for (int p = 0; p < 4; p++) {
        // ---- qkv both heads of pair p: 12 (typ,e,mi) tiles on waves 0..11 ----
        if (w < 12) {
            int typ = w >> 2, rem = w & 3;
            int e = rem >> 1, mq = rem & 1;
            int nt32g = typ*8 + 2*p + e;
            f32x16 acc = (f32x16)(0.f);
#pragma unroll
            for (int ks = 0; ks < 16; ks++) {
                bf16x8 ah = HFu[(mq*16+ks)*64 + lane];
                bf16x8 bh = wsv[U_QKV + (nt32g*16+ks)*64 + lane];
                acc = MFMA32(ah, bh, acc);
            }
            float bb = attn_in_b[nt32g*32 + col32];
#pragma unroll
            for (int reg = 0; reg < 16; reg++) {
                int r32 = (reg&3) + 8*(reg>>2) + rbase;
                int m  = mq*32 + r32;        // seq index
                int cc = col32;              // col within head (0..31)
                short hv = (short)f2bf(acc[reg] + bb);
                if (typ == 0) {        // q: A-FO-16 (m=seq, k=cc)
                    sm[SH_A + e*2048 + ((m>>4)*64 + (m&15) + 16*(cc>>3))*8 + (cc&7)] = hv;
                } else if (typ == 1) { // k: B-FO-16 (k=cc, n=seq)
                    sm[SH_A + 4096 + e*2048 + ((m>>4)*64 + (m&15) + 16*(cc>>3))*8 + (cc&7)] = hv;
                } else {               // v: B-FO-16 (k=seq, n=cc)
                    sm[SH_A + 8192 + e*2048 +
                       (((cc>>4)*2 + (m>>5))*64 + (cc&15) + 16*((m&31)>>3))*8 + (m&7)] = hv;
                }
            }
        }
        __syncthreads();   // B1

        // ---- scores, both heads: wave does tile (mi16 = w>>2, ni = w&3) per head ----
        {
            int mi16 = w >> 2, ni = w & 3;
#pragma unroll
            for (int e = 0; e < 2; e++) {
                bf16x8 ah = *(const bf16x8*)&sm[SH_A + e*2048 +        (mi16*64 + lane)*8];
                bf16x8 bh = *(const bf16x8*)&sm[SH_A + 4096 + e*2048 + (ni*64 + lane)*8];
                f32x4 sacc = (f32x4){0.f,0.f,0.f,0.f};
                sacc = MFMA16(ah, bh, sacc);
                float* SBe = smf + FB_SB + e*4160;
#pragma unroll
                for (int reg = 0; reg < 4; reg++) {
                    int m = mi16*16 + quad*4 + reg;
                    SBe[m*65 + ni*16 + lcol] = sacc[reg] * 0.17677669529663687f;
                }
            }
        }
        __syncthreads();   // B2

        // ---- softmax both heads (8 lanes/row) + fused pF write ----
        {
            int e  = tid >> 9;
            int r  = (tid >> 3) & 63;
            int li = tid & 7;
            float* SBe = smf + FB_SB + e*4160;
            float v[8];
#pragma unroll
            for (int j = 0; j < 8; j++) v[j] = SBe[r*65 + li*8 + j];
            float mx = v[0];
#pragma unroll
            for (int j = 1; j < 8; j++) mx = fmaxf(mx, v[j]);
#pragma unroll
            for (int off = 4; off >= 1; off >>= 1) mx = fmaxf(mx, __shfl_xor(mx, off, 64));
            float s = 0.f;
#pragma unroll
            for (int j = 0; j < 8; j++) { v[j] = expf(v[j]-mx); s += v[j]; }
#pragma unroll
            for (int off = 4; off >= 1; off >>= 1) s += __shfl_xor(s, off, 64);
            float inv = 1.0f / s;
            bf16x8 hv;
#pragma unroll
            for (int j = 0; j < 8; j++) hv[j] = (short)f2bf(v[j]*inv);
            // pF A-FO-16 (m=r, k=li*8+j): unit=((r>>4)*2 + (li>>2))*64 + (r&15) + 16*(li&3)
            *(bf16x8*)&sm[SH_A + 12288 + e*4096 +
                          (((r>>4)*2 + (li>>2))*64 + (r&15) + 16*(li&3))*8] = hv;
        }
        __syncthreads();   // B3

        // ---- PV both heads: wave -> (e = w>>3, mi16 = w&3, ni = (w>>2)&1) ----
        {
            int e = w >> 3, idx = w & 7, mi16 = idx & 3, ni = idx >> 2;
            f32x4 pv = (f32x4){0.f,0.f,0.f,0.f};
#pragma unroll
            for (int kb = 0; kb < 2; kb++) {
                bf16x8 ah = *(const bf16x8*)&sm[SH_A + 12288 + e*4096 + ((mi16*2+kb)*64 + lane)*8];
                bf16x8 bh = *(const bf16x8*)&sm[SH_A + 8192  + e*2048 + ((ni*2+kb)*64 + lane)*8];
                pv = MFMA16(ah, bh, pv);
            }
            // aoF A-FO-32 [2mi2][4ks][64][8]: (m, kstep = e*2+ni, klocal = lcol)
#pragma unroll
            for (int reg = 0; reg < 4; reg++) {
                int m = mi16*16 + quad*4 + reg;
                sm[SH_A + 20480 +
                   (((m>>5)*4 + e*2 + ni)*64 + (m&31) + 32*(lcol>>3))*8 + (lcol&7)] = (short)f2bf(pv[reg]);
            }
        }
        __syncthreads();   // B4

        // ---- attn_out partial (32x32): tile (mi2, ntf), K = this pair (4 ksteps) ----
        {
#pragma unroll
            for (int ks = 0; ks < 4; ks++) {
                bf16x8 ah = *(const bf16x8*)&sm[SH_A + 20480 + ((mi2*4+ks)*64 + lane)*8];
                bf16x8 bh = wsv[U_WO + (ntf*16 + 4*p + ks)*64 + lane];
                aoacc = MFMA32(ah, bh, aoacc);
            }
        }
        // no barrier: next writes to aoF are 3 barriers away
    }

    // ---------- residual += attn_out + bias (RMW h, own tile) ----------
    {
        int n = ntf*32 + col32;
        float bb = attn_out_b[n];
#pragma unroll
        for (int reg = 0; reg < 16; reg++) {
            int r32 = (reg&3) + 8*(reg>>2) + rbase;
            int uu = (((mi2*16 + (n>>4))*64) + r32 + 32*((n>>3)&1))*8 + (n&7);
            float val = bf2f((unsigned short)sm[SH_H + uu]) + aoacc[reg] + bb;
            sm[SH_H + uu] = (short)f2bf(val);
        }
    }

    // ---------- LayerNorm on h A-FO-32 (16 lanes/row) ----------
    auto layernormFO = [&](const float* __restrict__ g, const float* __restrict__ bt) {
        __syncthreads();                       // writers (resid) -> readers
        int m = tid >> 4, s = tid & 15;        // s = kb
        int ub = ((m>>5)*16 + s)*64 + (m&31);
        bf16x8 h0 = HFu[ub];                   // oct 0: k = s*16 + j
        bf16x8 h1 = HFu[ub + 32];              // oct 1: k = s*16 + 8 + j
        float v[16];
#pragma unroll
        for (int j = 0; j < 8; j++) {
            v[j]   = bf2f((unsigned short)h0[j]);
            v[8+j] = bf2f((unsigned short)h1[j]);
        }
        float sum = 0.f;
#pragma unroll
        for (int i = 0; i < 16; i++) sum += v[i];
#pragma unroll
        for (int off = 8; off >= 1; off >>= 1) sum += __shfl_xor(sum, off, 64);
        float mean = sum * (1.0f/256.0f);
        float s2 = 0.f;
#pragma unroll
        for (int i = 0; i < 16; i++) { float d = v[i] - mean; s2 += d*d; }
#pragma unroll
        for (int off = 8; off >= 1; off >>= 1) s2 += __shfl_xor(s2, off, 64);
        float rr = 1.0f / sqrtf(s2 * (1.0f/256.0f) + 1e-5f);
        bf16x8 o0, o1;
#pragma unroll
        for (int j = 0; j < 8; j++) {
            int k0 = s*16 + j, k1 = s*16 + 8 + j;
            o0[j] = (short)f2bf((v[j]   - mean) * rr * g[k0] + bt[k0]);
            o1[j] = (short)f2bf((v[8+j] - mean) * rr * g[k1] + bt[k1]);
        }
        ((bf16x8*)&sm[SH_H])[ub]      = o0;
        ((bf16x8*)&sm[SH_H])[ub + 32] = o1;
        __syncthreads();
    };
    layernormFO(ln1_g, ln1_b);

    // ---------- FFN: 4 chunks of 256 cols (32x32) ----------
    f32x16 f2acc = (f32x16)(0.f);   // ffn2 accum: tile (mi2, ntf)

    for (int c = 0; c < 4; c++) {
        // ffn1: tile (mi2, nt32g = c*8 + ntf), K=256
        f32x16 a1 = (f32x16)(0.f);
#pragma unroll
        for (int ks = 0; ks < 16; ks++) {
            bf16x8 ah = HFu[(mi2*16+ks)*64 + lane];
            bf16x8 bh = wsv[U_F1 + ((c*8+ntf)*16 + ks)*64 + lane];
            a1 = MFMA32(ah, bh, a1);
        }
        __syncthreads();   // prev chunk's ffn2 readers of f1 done
        // epilogue: relu -> f1 A-FO-32 [2mi][16kb][64][8]
        {
            int nG = (c*8 + ntf)*32 + col32;
            int kk = ntf*32 + col32;           // col within 256-chunk
            float bb = ffn_b1[nG];
#pragma unroll
            for (int reg = 0; reg < 16; reg++) {
                int r32 = (reg&3) + 8*(reg>>2) + rbase;
                float val = a1[reg] + bb;
                val = val > 0.f ? val : 0.f;
                sm[SH_A + (((mi2*16 + (kk>>4))*64) + r32 + 32*((kk>>3)&1))*8 + (kk&7)] = (short)f2bf(val);
            }
        }
        __syncthreads();
        // ffn2 partial: tile (mi2, ntf), K-chunk c
#pragma unroll
        for (int ks = 0; ks < 16; ks++) {
            bf16x8 ah = *(const bf16x8*)&sm[SH_A + ((mi2*16+ks)*64 + lane)*8];
            bf16x8 bh = wsv[U_F2 + (ntf*64 + c*16 + ks)*64 + lane];
            f2acc = MFMA32(ah, bh, f2acc);
        }
        // barrier at top of next iteration protects f1 overwrite
    }
    // residual += ffn2 + bias
    {
        int n = ntf*32 + col32;
        float bb = ffn_b2[n];
#pragma unroll
        for (int reg = 0; reg < 16; reg++) {
            int r32 = (reg&3) + 8*(reg>>2) + rbase;
            int uu = (((mi2*16 + (n>>4))*64) + r32 + 32*((n>>3)&1))*8 + (n&7);
            float val = bf2f((unsigned short)sm[SH_H + uu]) + f2acc[reg] + bb;
            sm[SH_H + uu] = (short)f2bf(val);
        }
    }
    layernormFO(ln2_g, ln2_b);

    // ---------- kproj (32x32): K = enc @ k_w + k_b -> SH_H becomes B-FO-16 ----------
    {
        f32x16 kacc = (f32x16)(0.f);
#pragma unroll
        for (int ks = 0; ks < 16; ks++) {
            bf16x8 ah = HFu[(mi2*16+ks)*64 + lane];
            bf16x8 bh = wsv[U_KW + (ntf*16+ks)*64 + lane];
            kacc = MFMA32(ah, bh, kacc);
        }
        __syncthreads();   // all enc reads complete before overwrite
        int n = ntf*32 + col32;      // dim d
        float bb = k_b[n];
#pragma unroll
        for (int reg = 0; reg < 16; reg++) {
            int r32 = (reg&3) + 8*(reg>>2) + rbase;
            int m = mi2*32 + r32;    // seq
            // B-FO-16 for S: (k=n, n'=m): [nt16=m>>4][kb32=n>>5][ (m&15)+16*((n&31)>>3) ][n&7]
            sm[SH_H + (((m>>4)*8 + (n>>5))*64 + (m&15) + 16*((n&31)>>3))*8 + (n&7)] =
                (short)f2bf(kacc[reg] + bb);
        }
    }
    __syncthreads();

    // ---------- S = Q @ K^T (16x16): 16 tiles ----------
    {
        int mi = w >> 2, nt = w & 3;
        f32x4 sacc = (f32x4){0.f,0.f,0.f,0.f};
#pragma unroll
        for (int kb = 0; kb < 8; kb++) {
            bf16x8 bh = HFu[(nt*8+kb)*64 + lane];
            bf16x8 ah = wsv[U_Q + (mi*8+kb)*64 + lane];
            sacc = MFMA16(ah, bh, sacc);
        }
#pragma unroll
        for (int reg = 0; reg < 4; reg++) {
            int t = mi*16 + quad*4 + reg;
            SB0[t*65 + nt*16 + lcol] = sacc[reg];
        }
    }
    __syncthreads();

    // ---------- greedy pointer decode (wave 0, lane n) ----------
    if (tid < 64) {
        int ln = tid;
        bool alive = true;
        float* outb = out + (size_t)b * (64*64);
        for (int t = 0; t < 64; t++) {
            float v  = SB0[t*65 + ln];
            float lv = alive ? v : NEG_FILL;
            outb[t*64 + ln] = lv;
            float bv = lv; int bi = ln;
#pragma unroll
            for (int off = 32; off >= 1; off >>= 1) {
                float ov = __shfl_xor(bv, off, 64);
                int   oi = __shfl_xor(bi, off, 64);
                if (ov > bv || (ov == bv && oi < bi)) { bv = ov; bi = oi; }
            }
            if (bi == ln) alive = false;
        }
    }
}

extern "C" void kernel_launch(void* const* d_in, const int* in_sizes, int n_in,
                              void* d_out, int out_size, void* d_ws, size_t ws_size,
                              hipStream_t stream) {
    (void)in_sizes; (void)n_in; (void)out_size; (void)ws_size;  // needs ws_size >= 1,802,240 B
    const float* x          = (const float*)d_in[0];
    const float* ve_w1      = (const float*)d_in[1];
    const float* ve_b1      = (const float*)d_in[2];
    const float* ve_w2      = (const float*)d_in[3];
    const float* ve_b2      = (const float*)d_in[4];
    const float* pos_emb    = (const float*)d_in[5];
    const float* attn_in_w  = (const float*)d_in[6];
    const float* attn_in_b  = (const float*)d_in[7];
    const float* attn_out_w = (const float*)d_in[8];
    const float* attn_out_b = (const float*)d_in[9];
    const float* ffn_w1     = (const float*)d_in[10];
    const float* ffn_b1     = (const float*)d_in[11];
    const float* ffn_w2     = (const float*)d_in[12];
    const float* ffn_b2     = (const float*)d_in[13];
    const float* ln1_g      = (const float*)d_in[14];
    const float* ln1_b      = (const float*)d_in[15];
    const float* ln2_g      = (const float*)d_in[16];
    const float* ln2_b      = (const float*)d_in[17];
    const float* rank_emb   = (const float*)d_in[18];
    const float* q_w        = (const float*)d_in[19];
    const float* q_b        = (const float*)d_in[20];
    const float* k_w        = (const float*)d_in[21];
    const float* k_b        = (const float*)d_in[22];
    float* outp = (float*)d_out;
    short* wsp  = (short*)d_ws;

    (void)hipFuncSetAttribute((const void*)fused_kernel,
                              hipFuncAttributeMaxDynamicSharedMemorySize,
                              (int)LDS_BYTES);

    hipLaunchKernelGGL(prep_q, dim3(64), dim3(256), 0, stream, rank_emb, q_w, q_b, wsp);
    hipLaunchKernelGGL(prep_w, dim3(432), dim3(256), 0, stream,
                       ve_w2, attn_in_w, attn_out_w, ffn_w1, ffn_w2, k_w, wsp);
    hipLaunchKernelGGL(fused_kernel, dim3(4096), dim3(1024), LDS_BYTES, stream,
                       x, ve_w1, ve_b1, ve_b2, pos_emb,
                       attn_in_b, attn_out_b,
                       ffn_b1, ffn_b2,
                       ln1_g, ln1_b, ln2_g, ln2_b,
                       k_b, (const short*)wsp, outp);
}

// Round 8
// 1488.114 us; speedup vs baseline: 1.0690x; 1.0690x over previous
//
#include <hip/hip_runtime.h>
#include <math.h>

// ============================================================
// PointerDecoderSort — MFMA bf16. R8 = R6 base (16x16 for all
// scatter-epilogue GEMMs: phase1b/qkv/ffn1/kproj — R7 showed 32x32
// C/D scatters are ~8-way bank-conflicted, doubling conflict cycles)
// + 32x32 ONLY for accumulator-only partials (attn_out, ffn2: halves
// their A-fragment LDS reads, no new scatters)
// + R7's barrier reductions (both-heads scores/softmax->pF fused/PV:
// 4 barriers per head-pair instead of ~11).
//
// Layout facts:
//   16x16x32: A[m=lane&15][k=(lane>>4)*8+j]; B[k=(lane>>4)*8+j][n=lane&15]
//             C/D: col=lane&15, row=(lane>>4)*4+reg            (m89/m91)
//   32x32x16: A[m=lane&31][k=(lane>>5)*8+j]; B[k=(lane>>5)*8+j][n=lane&31]
//             C/D: col=lane&31, row=(reg&3)+8*(reg>>2)+4*(lane>>5) (m74/m101)
// ============================================================

typedef __attribute__((ext_vector_type(8)))  short bf16x8;
typedef __attribute__((ext_vector_type(4)))  float f32x4;
typedef __attribute__((ext_vector_type(16))) float f32x16;

#define NEG_FILL (-3.0e38f)   // finite stand-in for -inf (inf-inf = nan in harness diff)

// ---- ws layout (units of 8 shorts = 16 B) ----
#define U_Q    0        // 2048  : Q rank queries, A-FO-16 [4mt][8kb32][64]
#define U_VE   2048     // 4096  : ve_w2  B-FO-16 [16nt][4kb][64]
#define U_QKV  6144     // 24576 : attn_in_w B-FO-16 [48nt][8kb][64]
#define U_WO   30720    // 8192  : attn_out_w B-FO-32 [8nt][16kb16][64]
#define U_F1   38912    // 32768 : ffn_w1 B-FO-16 [64nt][8kb][64]
#define U_F2   71680    // 32768 : ffn_w2 B-FO-32 [8nt][64kb16][64]
#define U_KW   104448   // 8192  : k_w B-FO-16 [16nt][8kb][64]
#define U_TOT  112640   // *16B = 1,802,240 B in d_ws

// ---- LDS layout (shorts) ----
#define SH_H  0         // h residual, A-FO-16 [4mt][8kb][64][8] = 16384
#define SH_A  16384     // phase-shared region, 24576 shorts:
//   ve phase : rbuf A-FO-16 [4mt][4kb][64][8] = 8192
//   ffn phase: f1 A-FO-32 [2mi2][16kb16][64][8] = 16384
//   attention: qF(e) SH_A + e*2048          A-FO-16 [4mt][64][8]
//              kF(e) SH_A + 4096  + e*2048  B-FO-16 [4nt][64][8]
//              vF(e) SH_A + 8192  + e*2048  B-FO-16 [2nt][2kb][64][8]
//              pF(e) SH_A + 12288 + e*4096  A-FO-16 [4mt][2kb][64][8]
//              aoF   SH_A + 20480           A-FO-32 [2mi2][4kb16][64][8] = 4096
#define SH_SHORTS 40960
// floats after shorts:
#define FB_SB   0       // 2 score buffers [2][64][65]
#define FB_XR   8320    // 64 x values
#define FB_FLOATS 8384
#define LDS_BYTES (SH_SHORTS*2 + FB_FLOATS*4)   // 115456

__device__ __forceinline__ unsigned short f2bf(float f){
  unsigned u = __float_as_uint(f);
  return (unsigned short)((u + 0x7FFFu + ((u>>16)&1u)) >> 16);
}
__device__ __forceinline__ float bf2f(unsigned short h){
  return __uint_as_float(((unsigned)h) << 16);
}

#define MFMA16(a,b,c) __builtin_amdgcn_mfma_f32_16x16x32_bf16((a),(b),(c),0,0,0)
#define MFMA32(a,b,c) __builtin_amdgcn_mfma_f32_32x32x16_bf16((a),(b),(c),0,0,0)

// ------------------------------------------------------------
__global__ void __launch_bounds__(256) prep_q(const float* __restrict__ rank_emb,
                                              const float* __restrict__ q_w,
                                              const float* __restrict__ q_b,
                                              short* __restrict__ wsp) {
    int t = blockIdx.x;
    int c = threadIdx.x;
    float acc = q_b[c];
    for (int d = 0; d < 256; d += 4) {
        acc += rank_emb[t*256 + d + 0] * q_w[(d+0)*256 + c]
             + rank_emb[t*256 + d + 1] * q_w[(d+1)*256 + c]
             + rank_emb[t*256 + d + 2] * q_w[(d+2)*256 + c]
             + rank_emb[t*256 + d + 3] * q_w[(d+3)*256 + c];
    }
    int kb = c >> 5, lane = ((c>>3)&3)*16 + (t&15), j = c & 7;
    int u = ((t>>4)*8 + kb)*64 + lane;
    wsp[(U_Q + u)*8 + j] = (short)f2bf(acc);
}

// ------------------------------------------------------------
// prep_w: B-FO-16 for ve/qkv/f1/kw; B-FO-32 for WO and F2.
// ------------------------------------------------------------
__global__ void __launch_bounds__(256) prep_w(const float* __restrict__ ve_w2,
                                              const float* __restrict__ attn_in_w,
                                              const float* __restrict__ attn_out_w,
                                              const float* __restrict__ ffn_w1,
                                              const float* __restrict__ ffn_w2,
                                              const float* __restrict__ k_w,
                                              short* __restrict__ wsp) {
    int r = blockIdx.x*256 + threadIdx.x;
    const float* w; int N, K, base;
    if (r < 4096)                { w = ve_w2;      N = 256;  K = 128;  base = U_VE;  }
    else if ((r -= 4096)  < 24576) { w = attn_in_w;  N = 768;  K = 256;  base = U_QKV; }
    else if ((r -= 24576) < 8192)  { w = attn_out_w; N = 256;  K = 256;  base = U_WO;  }
    else if ((r -= 8192)  < 32768) { w = ffn_w1;     N = 1024; K = 256;  base = U_F1;  }
    else if ((r -= 32768) < 32768) { w = ffn_w2;     N = 256;  K = 1024; base = U_F2;  }
    else     { r -= 32768;           w = k_w;        N = 256;  K = 256;  base = U_KW;  }
    int lane = r & 63;
    int n, k0;
    if (base == U_WO || base == U_F2) {        // B-FO-32
        int KB = K >> 4;
        int kb = (r >> 6) % KB;
        int nt = r / (64 * KB);
        n  = nt*32 + (lane & 31);
        k0 = kb*16 + (lane >> 5)*8;
    } else {                                   // B-FO-16
        int KB = K >> 5;
        int kb = (r >> 6) % KB;
        int nt = r / (64 * KB);
        n  = nt*16 + (lane & 15);
        k0 = kb*32 + (lane >> 4)*8;
    }
    bf16x8 hv;
#pragma unroll
    for (int j = 0; j < 8; j++) hv[j] = (short)f2bf(w[(size_t)(k0 + j)*N + n]);
    *(bf16x8*)&wsp[(size_t)(base + r) * 8] = hv;
}

// ------------------------------------------------------------
// fused per-batch-element kernel: 1024 threads = 16 waves
// ------------------------------------------------------------
__global__ void __launch_bounds__(1024, 4) fused_kernel(
    const float* __restrict__ x,
    const float* __restrict__ ve_w1, const float* __restrict__ ve_b1,
    const float* __restrict__ ve_b2,
    const float* __restrict__ pos_emb,
    const float* __restrict__ attn_in_b,
    const float* __restrict__ attn_out_b,
    const float* __restrict__ ffn_b1, const float* __restrict__ ffn_b2,
    const float* __restrict__ ln1_g, const float* __restrict__ ln1_b,
    const float* __restrict__ ln2_g, const float* __restrict__ ln2_b,
    const float* __restrict__ k_b,
    const short* __restrict__ wsp,
    float* __restrict__ out)
{
    extern __shared__ short sm[];
    float* smf  = (float*)(sm + SH_SHORTS);
    float* SB0  = smf + FB_SB;           // [64][65] (also final S / decode)
    float* xrow = smf + FB_XR;

    const int tid  = threadIdx.x;
    const int b    = blockIdx.x;
    const int w    = tid >> 6;     // 0..15
    const int lane = tid & 63;
    const int quad = lane >> 4;    // 16x16 use
    const int lcol = lane & 15;    // 16x16 use
    const int col32 = lane & 31;   // 32x32 use
    const int rbase = 4*(lane>>5); // 32x32 C/D row base

    // 32x32 partial-GEMM tile ownership
    const int mi2 = w >> 3;        // 0..1
    const int ntf = w & 7;         // 0..7

    const bf16x8* wsv = (const bf16x8*)wsp;
    const bf16x8* HFu = (const bf16x8*)&sm[SH_H];
    bf16x8* HFw = (bf16x8*)&sm[SH_H];

    // ---------- phase 0: x row ----------
    if (tid < 64) xrow[tid] = x[b*64 + tid];
    __syncthreads();

    // ---------- phase 1a: rbuf = relu(x*w1+b1) -> A-FO-16 ----------
    {
        int u = tid;
        int l3 = u & 63, kb = (u >> 6) & 3, mt = u >> 8;
        int m  = mt*16 + (l3 & 15);
        int k0 = kb*32 + (l3 >> 4)*8;
        float xv = xrow[m];
        bf16x8 hv;
#pragma unroll
        for (int j = 0; j < 8; j++) {
            float f = xv * ve_w1[k0 + j] + ve_b1[k0 + j];
            hv[j] = (short)f2bf(f > 0.f ? f : 0.f);
        }
        *(bf16x8*)&sm[SH_A + u*8] = hv;
    }
    __syncthreads();

    // ---------- phase 1b: h = rbuf @ ve_w2 + b2 + pos (16x16) ----------
    {
        int nt = w;
        f32x4 acc[4];
#pragma unroll
        for (int mi = 0; mi < 4; mi++) acc[mi] = (f32x4){0.f,0.f,0.f,0.f};
#pragma unroll
        for (int kb = 0; kb < 4; kb++) {
            bf16x8 bh = wsv[U_VE + (nt*4+kb)*64 + lane];
#pragma unroll
            for (int mi = 0; mi < 4; mi++) {
                bf16x8 ah = *(const bf16x8*)&sm[SH_A + ((mi*4+kb)*64 + lane)*8];
                acc[mi] = MFMA16(ah, bh, acc[mi]);
            }
        }
        __syncthreads();   // rbuf reads complete
        int n = nt*16 + lcol;
#pragma unroll
        for (int mi = 0; mi < 4; mi++)
#pragma unroll
            for (int reg = 0; reg < 4; reg++) {
                int m = mi*16 + quad*4 + reg;
                float val = acc[mi][reg] + ve_b2[n] + pos_emb[m*256 + n];
                int kb2 = n >> 5, l2 = ((n>>3)&3)*16 + (m&15), j2 = n & 7;
                sm[SH_H + ((mi*8 + kb2)*64 + l2)*8 + j2] = (short)f2bf(val);
            }
    }
    __syncthreads();

    // ---------- attention: head pairs, 4 barriers per pair ----------
    f32x16 aoacc = (f32x16)(0.f);   // attn-out 32x32 accum: tile (mi2, ntf)

    for (int p = 0; p < 4; p++) {
        // ---- qkv for pair p (16x16): 12 ntiles on waves 0..11, both heads ----
        if (w < 12) {
            int typ = w >> 2, il = w & 3;
            int ntg = (typ == 0) ? (4*p + il) : (typ == 1) ? (16 + 4*p + il) : (32 + 4*p + il);
            f32x4 acc[4];
#pragma unroll
            for (int mi = 0; mi < 4; mi++) acc[mi] = (f32x4){0.f,0.f,0.f,0.f};
#pragma unroll
            for (int kb = 0; kb < 8; kb++) {
                bf16x8 bh = wsv[U_QKV + (ntg*8+kb)*64 + lane];
#pragma unroll
                for (int mi = 0; mi < 4; mi++) {
                    bf16x8 ah = HFu[(mi*8+kb)*64 + lane];
                    acc[mi] = MFMA16(ah, bh, acc[mi]);
                }
            }
            int e = il >> 1, ch = il & 1;
#pragma unroll
            for (int mi = 0; mi < 4; mi++)
#pragma unroll
                for (int reg = 0; reg < 4; reg++) {
                    int m  = mi*16 + quad*4 + reg;
                    int cc = ch*16 + lcol;
                    short hv = (short)f2bf(acc[mi][reg] + attn_in_b[ntg*16 + lcol]);
                    if (typ == 0) {        // q: A-FO-16 (m=seq, k=cc)
                        int l2 = ((cc>>3)&3)*16 + (m&15), j2 = cc & 7;
                        sm[SH_A + e*2048 + (mi*64 + l2)*8 + j2] = hv;
                    } else if (typ == 1) { // k: B-FO-16 (k=cc, n=seq)
                        int l2 = ((cc>>3)&3)*16 + (m&15), j2 = cc & 7;
                        sm[SH_A + 4096 + e*2048 + ((m>>4)*64 + l2)*8 + j2] = hv;
                    } else {               // v: B-FO-16 (k=seq, n=cc)
                        int nt2 = cc >> 4, kb2 = m >> 5;
                        int l2 = ((m>>3)&3)*16 + (cc&15), j2 = m & 7;
                        sm[SH_A + 8192 + e*2048 + ((nt2*2 + kb2)*64 + l2)*8 + j2] = hv;
                    }
                }
        }
        __syncthreads();   // B1

        // ---- scores, both heads: wave (mi16 = w>>2, ni = w&3), e = 0,1 ----
        {
            int mi16 = w >> 2, ni = w & 3;
#pragma unroll
            for (int e = 0; e < 2; e++) {
                bf16x8 ah = *(const bf16x8*)&sm[SH_A + e*2048 +        (mi16*64 + lane)*8];
                bf16x8 bh = *(const bf16x8*)&sm[SH_A + 4096 + e*2048 + (ni*64 + lane)*8];
                f32x4 sacc = (f32x4){0.f,0.f,0.f,0.f};
                sacc = MFMA16(ah, bh, sacc);
                float* SBe = smf + FB_SB + e*4160;
#pragma unroll
                for (int reg = 0; reg < 4; reg++) {
                    int m = mi16*16 + quad*4 + reg;
                    SBe[m*65 + ni*16 + lcol] = sacc[reg] * 0.17677669529663687f;
                }
            }
        }
        __syncthreads();   // B2

        // ---- softmax both heads (8 lanes/row) + fused pF write ----
        {
            int e  = tid >> 9;
            int r  = (tid >> 3) & 63;
            int li = tid & 7;
            float* SBe = smf + FB_SB + e*4160;
            float v[8];
#pragma unroll
            for (int j = 0; j < 8; j++) v[j] = SBe[r*65 + li*8 + j];
            float mx = v[0];
#pragma unroll
            for (int j = 1; j < 8; j++) mx = fmaxf(mx, v[j]);
#pragma unroll
            for (int off = 4; off >= 1; off >>= 1) mx = fmaxf(mx, __shfl_xor(mx, off, 64));
            float s = 0.f;
#pragma unroll
            for (int j = 0; j < 8; j++) { v[j] = expf(v[j]-mx); s += v[j]; }
#pragma unroll
            for (int off = 4; off >= 1; off >>= 1) s += __shfl_xor(s, off, 64);
            float inv = 1.0f / s;
            bf16x8 hv;
#pragma unroll
            for (int j = 0; j < 8; j++) hv[j] = (short)f2bf(v[j]*inv);
            // pF A-FO-16 (m=r, k=li*8+j)
            *(bf16x8*)&sm[SH_A + 12288 + e*4096 +
                          (((r>>4)*2 + (li>>2))*64 + (r&15) + 16*(li&3))*8] = hv;
        }
        __syncthreads();   // B3

        // ---- PV both heads (16x16): wave -> (e = w>>3, mi16 = w&3, ni = (w>>2)&1) ----
        {
            int e = w >> 3, idx = w & 7, mi16 = idx & 3, ni = idx >> 2;
            f32x4 pv = (f32x4){0.f,0.f,0.f,0.f};
#pragma unroll
            for (int kb = 0; kb < 2; kb++) {
                bf16x8 ah = *(const bf16x8*)&sm[SH_A + 12288 + e*4096 + ((mi16*2+kb)*64 + lane)*8];
                bf16x8 bh = *(const bf16x8*)&sm[SH_A + 8192  + e*2048 + ((ni*2+kb)*64 + lane)*8];
                pv = MFMA16(ah, bh, pv);
            }
            // aoF A-FO-32 [2mi2][4kb16][64][8]: pair-local k = e*32 + ni*16 + lcol
#pragma unroll
            for (int reg = 0; reg < 4; reg++) {
                int m = mi16*16 + quad*4 + reg;
                sm[SH_A + 20480 +
                   (((m>>5)*4 + e*2 + ni)*64 + (m&31) + 32*(lcol>>3))*8 + (lcol&7)] = (short)f2bf(pv[reg]);
            }
        }
        __syncthreads();   // B4

        // ---- attn_out partial (32x32): tile (mi2, ntf), K = this pair ----
        {
#pragma unroll
            for (int ks = 0; ks < 4; ks++) {
                bf16x8 ah = *(const bf16x8*)&sm[SH_A + 20480 + ((mi2*4+ks)*64 + lane)*8];
                bf16x8 bh = wsv[U_WO + (ntf*16 + 4*p + ks)*64 + lane];
                aoacc = MFMA32(ah, bh, aoacc);
            }
        }
        // no barrier needed: aoF next written after B3 of next pair;
        // qkv (after next loop head) writes regions disjoint from aoF.
    }

    // ---------- residual += attn_out + bias (32x32 C/D -> h A-FO-16 RMW) ----------
    {
        int n = ntf*32 + col32;
        float bb = attn_out_b[n];
#pragma unroll
        for (int reg = 0; reg < 16; reg++) {
            int r32 = (reg&3) + 8*(reg>>2) + rbase;
            int m = mi2*32 + r32;
            int uu = (((m>>4)*8 + (n>>5))*64 + ((n>>3)&3)*16 + (m&15))*8 + (n&7);
            float val = bf2f((unsigned short)sm[SH_H + uu]) + aoacc[reg] + bb;
            sm[SH_H + uu] = (short)f2bf(val);
        }
    }
    __syncthreads();

    // ---------- LayerNorm on h A-FO-16 (16 lanes/row shuffle) ----------
    auto layernormFO = [&](const float* __restrict__ g, const float* __restrict__ bt) {
        int m = tid >> 4, s = tid & 15;
        int kb = s >> 1;
        int qb = (s & 1) * 2;
        int ub = ((m>>4)*8 + kb)*64 + (m&15);
        bf16x8 h0 = HFu[ub + (qb+0)*16];
        bf16x8 h1 = HFu[ub + (qb+1)*16];
        float v[16];
#pragma unroll
        for (int j = 0; j < 8; j++) {
            v[j]   = bf2f((unsigned short)h0[j]);
            v[8+j] = bf2f((unsigned short)h1[j]);
        }
        float sum = 0.f;
#pragma unroll
        for (int i = 0; i < 16; i++) sum += v[i];
#pragma unroll
        for (int off = 8; off >= 1; off >>= 1) sum += __shfl_xor(sum, off, 64);
        float mean = sum * (1.0f/256.0f);
        float s2 = 0.f;
#pragma unroll
        for (int i = 0; i < 16; i++) { float d = v[i] - mean; s2 += d*d; }
#pragma unroll
        for (int off = 8; off >= 1; off >>= 1) s2 += __shfl_xor(s2, off, 64);
        float r = 1.0f / sqrtf(s2 * (1.0f/256.0f) + 1e-5f);
        bf16x8 o0, o1;
#pragma unroll
        for (int j = 0; j < 8; j++) {
            int k0 = kb*32 + (qb+0)*8 + j;
            int k1 = kb*32 + (qb+1)*8 + j;
            o0[j] = (short)f2bf((v[j]   - mean) * r * g[k0] + bt[k0]);
            o1[j] = (short)f2bf((v[8+j] - mean) * r * g[k1] + bt[k1]);
        }
        HFw[ub + (qb+0)*16] = o0;
        HFw[ub + (qb+1)*16] = o1;
        __syncthreads();
    };
    layernormFO(ln1_g, ln1_b);

    // ---------- FFN: 4 chunks of 256 cols ----------
    f32x16 f2acc = (f32x16)(0.f);   // ffn2 32x32 accum: tile (mi2, ntf)

    for (int c = 0; c < 4; c++) {
        // ffn1 (16x16): wave owns ntile nt1 = c*16 + w, all 4 mi; K=256
        f32x4 a1[4];
#pragma unroll
        for (int mi = 0; mi < 4; mi++) a1[mi] = (f32x4){0.f,0.f,0.f,0.f};
        int nt1 = c*16 + w;
#pragma unroll
        for (int kb = 0; kb < 8; kb++) {
            bf16x8 bh = wsv[U_F1 + (nt1*8 + kb)*64 + lane];
#pragma unroll
            for (int mi = 0; mi < 4; mi++) {
                bf16x8 ah = HFu[(mi*8+kb)*64 + lane];
                a1[mi] = MFMA16(ah, bh, a1[mi]);
            }
        }
        __syncthreads();   // prev chunk's ffn2 readers of f1 done
        // epilogue: relu -> f1 A-FO-32 [2mi2][16kb16][64][8]
#pragma unroll
        for (int mi = 0; mi < 4; mi++)
#pragma unroll
            for (int reg = 0; reg < 4; reg++) {
                int m = mi*16 + quad*4 + reg;
                int n = nt1*16 + lcol;
                float val = a1[mi][reg] + ffn_b1[n];
                val = val > 0.f ? val : 0.f;
                // col within 256-chunk: kk = w*16 + lcol; kb16 = w
                sm[SH_A + (((m>>5)*16 + w)*64 + (m&31) + 32*(lcol>>3))*8 + (lcol&7)]
                    = (short)f2bf(val);
            }
        __syncthreads();
        // ffn2 partial (32x32): tile (mi2, ntf), K-chunk c (16 kb16)
#pragma unroll
        for (int ks = 0; ks < 16; ks++) {
            bf16x8 ah = *(const bf16x8*)&sm[SH_A + ((mi2*16+ks)*64 + lane)*8];
            bf16x8 bh = wsv[U_F2 + (ntf*64 + c*16 + ks)*64 + lane];
            f2acc = MFMA32(ah, bh, f2acc);
        }
        // barrier at top of next iteration protects f1 overwrite
    }
    __syncthreads();
    // residual += ffn2 + bias (32x32 C/D -> h A-FO-16 RMW)
    {
        int n = ntf*32 + col32;
        float bb = ffn_b2[n];
#pragma unroll
        for (int reg = 0; reg < 16; reg++) {
            int r32 = (reg&3) + 8*(reg>>2) + rbase;
            int m = mi2*32 + r32;
            int uu = (((m>>4)*8 + (n>>5))*64 + ((n>>3)&3)*16 + (m&15))*8 + (n&7);
            float val = bf2f((unsigned short)sm[SH_H + uu]) + f2acc[reg] + bb;
            sm[SH_H + uu] = (short)f2bf(val);
        }
    }
    __syncthreads();
    layernormFO(ln2_g, ln2_b);

    // ---------- kproj (16x16): K = enc @ k_w + k_b -> h becomes B-FO-16 ----------
    {
        f32x4 kacc[4];
#pragma unroll
        for (int mi = 0; mi < 4; mi++) kacc[mi] = (f32x4){0.f,0.f,0.f,0.f};
#pragma unroll
        for (int kb = 0; kb < 8; kb++) {
            bf16x8 bh = wsv[U_KW + (w*8+kb)*64 + lane];
#pragma unroll
            for (int mi = 0; mi < 4; mi++) {
                bf16x8 ah = HFu[(mi*8+kb)*64 + lane];
                kacc[mi] = MFMA16(ah, bh, kacc[mi]);
            }
        }
        __syncthreads();   // all enc reads complete before overwrite
        int n = w*16 + lcol;
#pragma unroll
        for (int mi = 0; mi < 4; mi++)
#pragma unroll
            for (int reg = 0; reg < 4; reg++) {
                int m = mi*16 + quad*4 + reg;     // seq
                int nt2 = m >> 4, kb2 = n >> 5;
                int l2 = ((n>>3)&3)*16 + (m&15), j2 = n & 7;
                sm[SH_H + ((nt2*8 + kb2)*64 + l2)*8 + j2] =
                    (short)f2bf(kacc[mi][reg] + k_b[n]);
            }
    }
    __syncthreads();

    // ---------- S = Q @ K^T (16x16): 16 tiles ----------
    {
        int mi = w >> 2, nt = w & 3;
        f32x4 sacc = (f32x4){0.f,0.f,0.f,0.f};
#pragma unroll
        for (int kb = 0; kb < 8; kb++) {
            bf16x8 bh = HFu[(nt*8+kb)*64 + lane];
            bf16x8 ah = wsv[U_Q + (mi*8+kb)*64 + lane];
            sacc = MFMA16(ah, bh, sacc);
        }
#pragma unroll
        for (int reg = 0; reg < 4; reg++) {
            int t = mi*16 + quad*4 + reg;
            SB0[t*65 + nt*16 + lcol] = sacc[reg];
        }
    }
    __syncthreads();

    // ---------- greedy pointer decode (wave 0, lane n) ----------
    if (tid < 64) {
        int ln = tid;
        bool alive = true;
        float* outb = out + (size_t)b * (64*64);
        for (int t = 0; t < 64; t++) {
            float v  = SB0[t*65 + ln];
            float lv = alive ? v : NEG_FILL;
            outb[t*64 + ln] = lv;
            float bv = lv; int bi = ln;
#pragma unroll
            for (int off = 32; off >= 1; off >>= 1) {
                float ov = __shfl_xor(bv, off, 64);
                int   oi = __shfl_xor(bi, off, 64);
                if (ov > bv || (ov == bv && oi < bi)) { bv = ov; bi = oi; }
            }
            if (bi == ln) alive = false;
        }
    }
}

extern "C" void kernel_launch(void* const* d_in, const int* in_sizes, int n_in,
                              void* d_out, int out_size, void* d_ws, size_t ws_size,
                              hipStream_t stream) {
    (void)in_sizes; (void)n_in; (void)out_size; (void)ws_size;  // needs ws_size >= 1,802,240 B
    const float* x          = (const float*)d_in[0];
    const float* ve_w1      = (const float*)d_in[1];
    const float* ve_b1      = (const float*)d_in[2];
    const float* ve_w2      = (const float*)d_in[3];
    const float* ve_b2      = (const float*)d_in[4];
    const float* pos_emb    = (const float*)d_in[5];
    const float* attn_in_w  = (const float*)d_in[6];
    const float* attn_in_b  = (const float*)d_in[7];
    const float* attn_out_w = (const float*)d_in[8];
    const float* attn_out_b = (const float*)d_in[9];
    const float* ffn_w1     = (const float*)d_in[10];
    const float* ffn_b1     = (const float*)d_in[11];
    const float* ffn_w2     = (const float*)d_in[12];
    const float* ffn_b2     = (const float*)d_in[13];
    const float* ln1_g      = (const float*)d_in[14];
    const float* ln1_b      = (const float*)d_in[15];
    const float* ln2_g      = (const float*)d_in[16];
    const float* ln2_b      = (const float*)d_in[17];
    const float* rank_emb   = (const float*)d_in[18];
    const float* q_w        = (const float*)d_in[19];
    const float* q_b        = (const float*)d_in[20];
    const float* k_w        = (const float*)d_in[21];
    const float* k_b        = (const float*)d_in[22];
    float* outp = (float*)d_out;
    short* wsp  = (short*)d_ws;

    (void)hipFuncSetAttribute((const void*)fused_kernel,
                              hipFuncAttributeMaxDynamicSharedMemorySize,
                              (int)LDS_BYTES);

    hipLaunchKernelGGL(prep_q, dim3(64), dim3(256), 0, stream, rank_emb, q_w, q_b, wsp);
    hipLaunchKernelGGL(prep_w, dim3(432), dim3(256), 0, stream,
                       ve_w2, attn_in_w, attn_out_w, ffn_w1, ffn_w2, k_w, wsp);
    hipLaunchKernelGGL(fused_kernel, dim3(4096), dim3(1024), LDS_BYTES, stream,
                       x, ve_w1, ve_b1, ve_b2, pos_emb,
                       attn_in_b, attn_out_b,
                       ffn_b1, ffn_b2,
                       ln1_g, ln1_b, ln2_g, ln2_b,
                       k_b, (const short*)wsp, outp);
}